// Round 11
// baseline (296.896 us; speedup 1.0000x reference)
//
#include <hip/hip_runtime.h>
#include <hip/hip_bf16.h>

#define NNODES 10000
#define NEDGES 160000
#define F_IN   50
#define HIDDEN 128
#define NCLS   121
#define DBIG   1024   // 8*128
#define MPAD   10112  // 79*128 = 158*64

typedef __attribute__((ext_vector_type(8))) short short8v;
typedef __attribute__((ext_vector_type(4))) float f32x4;
typedef __attribute__((ext_vector_type(4))) unsigned short u16x4;

#define GLD16(gsrc, ldst) \
  __builtin_amdgcn_global_load_lds((__attribute__((address_space(1))) const void*)(const void*)(gsrc), \
                                   (__attribute__((address_space(3))) void*)(void*)(ldst), 16, 0, 0)

// ---------------------------------------------------------------- CSR build
__global__ void hist_kernel(const int* __restrict__ ei, int* __restrict__ cnt,
                            int E_, int N_) {
    int e = blockIdx.x * blockDim.x + threadIdx.x;
    if (e >= E_ + N_) return;
    int dst = (e < E_) ? ei[E_ + e] : (e - E_);
    atomicAdd(&cnt[dst], 1);
}

// 1024-thread wave-shuffle scan (exclusive) over n ints
__global__ void scan_kernel(const int* __restrict__ cnt, int* __restrict__ row_ptr,
                            int n) {
    __shared__ int sums[16];
    __shared__ int stot;
    int tid = threadIdx.x, lane = tid & 63, wid = tid >> 6;
    int running = 0;
    for (int base = 0; base < n; base += 1024) {
        int i = base + tid;
        int v = (i < n) ? cnt[i] : 0;
        int x = v;
        #pragma unroll
        for (int o = 1; o < 64; o <<= 1) {
            int t = __shfl_up(x, o);
            if (lane >= o) x += t;
        }
        if (lane == 63) sums[wid] = x;
        __syncthreads();
        if (tid == 0) {
            int acc = 0;
            #pragma unroll
            for (int k = 0; k < 16; ++k) { int t = sums[k]; sums[k] = acc; acc += t; }
            stot = acc;
        }
        __syncthreads();
        if (i < n) row_ptr[i] = running + sums[wid] + x - v;  // exclusive
        running += stot;
        __syncthreads();
    }
    if (threadIdx.x == 0) row_ptr[n] = running;
}

__global__ void scatter_kernel(const int* __restrict__ ei,
                               const int* __restrict__ row_ptr,
                               int* __restrict__ cursor, int* __restrict__ esrc,
                               int E_, int N_) {
    int e = blockIdx.x * blockDim.x + threadIdx.x;
    if (e >= E_ + N_) return;
    int s, d;
    if (e < E_) { s = ei[e]; d = ei[E_ + e]; } else { s = d = e - E_; }
    int pos = row_ptr[d] + atomicAdd(&cursor[d], 1);
    esrc[pos] = s;
}

// ---------------------------------------------------------------- layer-1 folds
__global__ void fold_kernel(const float* __restrict__ W1,
                            const float* __restrict__ a_src,
                            const float* __restrict__ a_dst,
                            float* __restrict__ wfold) {
    int b = blockIdx.x;           // 16 blocks
    int h = b & 7, which = b >> 3;
    int k = threadIdx.x;          // 64
    const float* a = which ? a_dst : a_src;
    float dot = 0.f;
    if (k < F_IN) {
        for (int c = 0; c < HIDDEN; ++c)
            dot += W1[(size_t)k * DBIG + h * HIDDEN + c] * a[h * HIDDEN + c];
    }
    wfold[(which * 8 + h) * 64 + k] = dot;
}

__global__ void sdot1x_kernel(const float* __restrict__ x,
                              const float* __restrict__ wfold,
                              float* __restrict__ ssrc, float* __restrict__ sdst) {
    __shared__ float sh_x[16][52];
    __shared__ float sh_w[16][64];
    int tid = threadIdx.x;        // 256
    int n0 = blockIdx.x * 16;
    for (int i = tid; i < 16 * 64; i += 256) sh_w[i >> 6][i & 63] = wfold[i];
    for (int i = tid; i < 16 * F_IN; i += 256) {
        int nl = i / F_IN, k = i % F_IN;
        int n = n0 + nl;
        sh_x[nl][k] = (n < NNODES) ? x[(size_t)n * F_IN + k] : 0.f;
    }
    __syncthreads();
    int nl = tid >> 4, o = tid & 15;
    int n = n0 + nl;
    if (n >= NNODES) return;
    float s = 0.f;
    #pragma unroll
    for (int k = 0; k < F_IN; ++k) s += sh_x[nl][k] * sh_w[o][k];
    if (o < 8) ssrc[n * 8 + o] = s;
    else       sdst[n * 8 + (o - 8)] = s;
}

// layer-1 aggregation over X (50-wide). grid = MPAD (pad blocks write zeros).
__global__ void agg1_kernel(const float* __restrict__ x,
                            const float* __restrict__ ssrc,
                            const float* __restrict__ sdst,
                            const int* __restrict__ row_ptr,
                            const int* __restrict__ esrc,
                            __hip_bfloat16* __restrict__ YH,
                            __hip_bfloat16* __restrict__ YL) {
    int n = blockIdx.x;
    int tid = threadIdx.x;        // 64
    if (n >= NNODES) {            // pad rows -> zeros
        #pragma unroll
        for (int h = 0; h < 8; ++h) {
            size_t o = ((size_t)h * MPAD + n) * 64 + tid;
            YH[o] = __float2bfloat16(0.f);
            YL[o] = __float2bfloat16(0.f);
        }
        return;
    }
    __shared__ float m_s[8], inv_s[8], sd_s[8];
    __shared__ int sidx[64];
    __shared__ float coef[64][9];
    int row = row_ptr[n], end = row_ptr[n + 1];
    {
        int el = tid >> 3, hh = tid & 7;
        float sd = sdst[n * 8 + hh];
        float mymax = -1e30f;
        for (int e = row + el; e < end; e += 8) {
            float a = ssrc[esrc[e] * 8 + hh] + sd;
            a = (a >= 0.f) ? a : 0.2f * a;
            mymax = fmaxf(mymax, a);
        }
        #pragma unroll
        for (int o = 8; o < 64; o <<= 1) mymax = fmaxf(mymax, __shfl_xor(mymax, o));
        float mysum = 0.f;
        for (int e = row + el; e < end; e += 8) {
            float a = ssrc[esrc[e] * 8 + hh] + sd;
            a = (a >= 0.f) ? a : 0.2f * a;
            mysum += __expf(a - mymax);
        }
        #pragma unroll
        for (int o = 8; o < 64; o <<= 1) mysum += __shfl_xor(mysum, o);
        if (el == 0) { m_s[hh] = mymax; inv_s[hh] = 1.f / mysum; sd_s[hh] = sd; }
    }
    __syncthreads();
    float acc[8] = {};
    for (int cs = row; cs < end; cs += 64) {
        int nE = min(64, end - cs);
        if (tid < nE) {
            int s = esrc[cs + tid];
            sidx[tid] = s;
            #pragma unroll
            for (int h = 0; h < 8; ++h) {
                float a = ssrc[s * 8 + h] + sd_s[h];
                a = (a >= 0.f) ? a : 0.2f * a;
                coef[tid][h] = __expf(a - m_s[h]) * inv_s[h];
            }
        }
        __syncthreads();
        if (tid < F_IN) {
            for (int i = 0; i < nE; ++i) {
                float xv = x[(size_t)sidx[i] * F_IN + tid];
                #pragma unroll
                for (int h = 0; h < 8; ++h) acc[h] += coef[i][h] * xv;
            }
        }
        __syncthreads();
    }
    #pragma unroll
    for (int h = 0; h < 8; ++h) {
        float v = acc[h];
        __hip_bfloat16 hb = __float2bfloat16(v);
        size_t o = ((size_t)h * MPAD + n) * 64 + tid;
        YH[o] = hb;
        YL[o] = __float2bfloat16(v - __bfloat162float(hb));
    }
}

// ---------------------------------------------------------------- weight prep
__global__ void tsplit_kernel(const float* __restrict__ W, int K, int Nn, int Kpad,
                              __hip_bfloat16* __restrict__ bh,
                              __hip_bfloat16* __restrict__ bl) {
    __shared__ float sh[64][65];
    int k0 = blockIdx.x * 64, n0 = blockIdx.y * 64;
    int tid = threadIdx.x;
    int cc = tid & 63, rr = tid >> 6;
    #pragma unroll
    for (int i = 0; i < 16; ++i) {
        int r = rr + i * 4;
        int k = k0 + r, n = n0 + cc;
        sh[r][cc] = (k < K && n < Nn) ? W[(size_t)k * Nn + n] : 0.f;
    }
    __syncthreads();
    #pragma unroll
    for (int i = 0; i < 16; ++i) {
        int r = rr + i * 4;
        float v = sh[cc][r];
        __hip_bfloat16 h = __float2bfloat16(v);
        size_t o = (size_t)(n0 + r) * Kpad + k0 + cc;
        bh[o] = h;
        bl[o] = __float2bfloat16(v - __bfloat162float(h));
    }
}

// ---------------------------------------------------------------- MFMA GEMM (generic, layers 1&3)
template <int BM, int BN, int WM, int WN, bool EPI, bool MASKC, bool SDOT>
__global__ __launch_bounds__(256, 4)
void gemm_mfma(const __hip_bfloat16* __restrict__ Ah,
               const __hip_bfloat16* __restrict__ Al, int ldA, long sAz,
               const __hip_bfloat16* __restrict__ Bh,
               const __hip_bfloat16* __restrict__ Bl, int ldB, long sBz,
               float* __restrict__ C, int ldC, int M, int Nn, int K, int colPerZ,
               const float* __restrict__ bias,
               __hip_bfloat16* __restrict__ OH, __hip_bfloat16* __restrict__ OL,
               int swzNB,
               const float* __restrict__ adot_s, const float* __restrict__ adot_d,
               float* __restrict__ sdot_s, float* __restrict__ sdot_d,
               float* __restrict__ zeroPtr, int zeroCnt) {
    constexpr int MF = BM / (WM * 16);
    constexpr int NF = BN / (WN * 16);
    constexpr int TAB = BM * 64;   // bytes per tile (BM rows x 64B)
    constexpr int TBB = BN * 64;
    __shared__ char lds[2 * TAB + 2 * TBB];
    char* sAh = lds;
    char* sAl = lds + TAB;
    char* sBh = lds + 2 * TAB;
    char* sBl = lds + 2 * TAB + TBB;

    const int tid = threadIdx.x;
    if (zeroPtr) {
        int lb = ((blockIdx.z * gridDim.y + blockIdx.y) * gridDim.x + blockIdx.x)
                     * (int)blockDim.x + tid;
        if (lb < zeroCnt) zeroPtr[lb] = 0.f;
    }

    const int z = blockIdx.z;
    Ah += (size_t)z * sAz; Al += (size_t)z * sAz;
    Bh += (size_t)z * sBz; Bl += (size_t)z * sBz;

    int bx = blockIdx.x, by = blockIdx.y;
    if (swzNB) {
        int gx = gridDim.x;
        int lin = by * gx + bx;
        int c = lin & 7, i = lin >> 3;
        int nl = c * (swzNB >> 3) + i;
        bx = nl % gx;
        by = nl / gx;
    }

    const int lane = tid & 63;
    const int w = tid >> 6;
    const int wm = w / WN, wn = w % WN;
    const int row0 = by * BM;
    const int col0 = bx * BN;

    constexpr int nchA = BM / 16, nchB = BN / 16;
    constexpr int NCH = 2 * nchA + 2 * nchB;
    constexpr int NIT = NCH / 4;

    const int Rl = lane >> 3;
    const int sl = lane & 7;
    const int rl = 2 * Rl + (sl >> 2);

    const __hip_bfloat16* gsrc[NIT];
    char* ldsp[NIT];
    #pragma unroll
    for (int it = 0; it < NIT; ++it) {
        int lc = w + it * 4;
        const __hip_bfloat16* g; char* base; int ld; int r0;
        if (lc < nchA)              { g = Ah; base = sAh; ld = ldA; r0 = row0; }
        else if ((lc -= nchA) < nchA){ g = Al; base = sAl; ld = ldA; r0 = row0; }
        else if ((lc -= nchA) < nchB){ g = Bh; base = sBh; ld = ldB; r0 = col0; }
        else { lc -= nchB;            g = Bl; base = sBl; ld = ldB; r0 = col0; }
        int R = lc * 8 + Rl;
        int rowt = lc * 16 + rl;
        int psrc = (sl & 3) ^ (R & 3);
        gsrc[it] = g + (size_t)(r0 + rowt) * ld + psrc * 8;
        ldsp[it] = base + lc * 1024;
    }

    f32x4 acc[MF][NF];
    #pragma unroll
    for (int i = 0; i < MF; ++i)
        #pragma unroll
        for (int j = 0; j < NF; ++j) acc[i][j] = (f32x4){0.f, 0.f, 0.f, 0.f};

    for (int k0 = 0; k0 < K; k0 += 32) {
        __syncthreads();
        #pragma unroll
        for (int it = 0; it < NIT; ++it) {
            GLD16(gsrc[it], ldsp[it]);
            gsrc[it] += 32;
        }
        __syncthreads();
        short8v ah[MF], al[MF];
        #pragma unroll
        for (int mf = 0; mf < MF; ++mf) {
            int r = wm * (BM / WM) + mf * 16 + (lane & 15);
            int p = lane >> 4;
            int off = (r >> 1) * 128 + (r & 1) * 64 + ((p ^ ((r >> 1) & 3)) << 4);
            ah[mf] = *(const short8v*)(sAh + off);
            al[mf] = *(const short8v*)(sAl + off);
        }
        #pragma unroll
        for (int nf = 0; nf < NF; ++nf) {
            int r = wn * (BN / WN) + nf * 16 + (lane & 15);
            int p = lane >> 4;
            int off = (r >> 1) * 128 + (r & 1) * 64 + ((p ^ ((r >> 1) & 3)) << 4);
            short8v bh = *(const short8v*)(sBh + off);
            short8v bl = *(const short8v*)(sBl + off);
            #pragma unroll
            for (int mf = 0; mf < MF; ++mf) {
                acc[mf][nf] = __builtin_amdgcn_mfma_f32_16x16x32_bf16(ah[mf], bh, acc[mf][nf], 0, 0, 0);
                acc[mf][nf] = __builtin_amdgcn_mfma_f32_16x16x32_bf16(ah[mf], bl, acc[mf][nf], 0, 0, 0);
                acc[mf][nf] = __builtin_amdgcn_mfma_f32_16x16x32_bf16(al[mf], bh, acc[mf][nf], 0, 0, 0);
            }
        }
    }

    float ps[MF][4], pd[MF][4];
    if (SDOT) {
        #pragma unroll
        for (int mf = 0; mf < MF; ++mf)
            #pragma unroll
            for (int r2 = 0; r2 < 4; ++r2) { ps[mf][r2] = 0.f; pd[mf][r2] = 0.f; }
    }

    #pragma unroll
    for (int mf = 0; mf < MF; ++mf) {
        int m = row0 + wm * (BM / WM) + mf * 16 + ((lane >> 4) << 2);
        #pragma unroll
        for (int nf = 0; nf < NF; ++nf) {
            int ln = col0 + wn * (BN / WN) + nf * 16 + (lane & 15);
            if (MASKC && ln >= Nn) continue;
            int gcol = z * colPerZ + ln;
            f32x4 v = acc[mf][nf];
            if (SDOT) {
                float as = adot_s[gcol], ad = adot_d[gcol];
                #pragma unroll
                for (int r2 = 0; r2 < 4; ++r2) {
                    ps[mf][r2] += v[r2] * as;
                    pd[mf][r2] += v[r2] * ad;
                }
            }
            if (EPI) {
                float bv = bias[gcol];
                #pragma unroll
                for (int r2 = 0; r2 < 4; ++r2) {
                    if (MASKC && m + r2 >= M) continue;
                    float o = v[r2] + bv;
                    o = (o > 0.f) ? o : __expf(o) - 1.f;
                    __hip_bfloat16 hb = __float2bfloat16(o);
                    size_t idx = (size_t)(m + r2) * ldC + gcol;
                    OH[idx] = hb;
                    OL[idx] = __float2bfloat16(o - __bfloat162float(hb));
                }
            } else {
                #pragma unroll
                for (int r2 = 0; r2 < 4; ++r2) {
                    if (MASKC && m + r2 >= M) continue;
                    C[(size_t)(m + r2) * ldC + gcol] = v[r2];
                }
            }
        }
    }

    if (SDOT) {
        #pragma unroll
        for (int mf = 0; mf < MF; ++mf) {
            #pragma unroll
            for (int r2 = 0; r2 < 4; ++r2) {
                float vs = ps[mf][r2], vd = pd[mf][r2];
                #pragma unroll
                for (int o = 1; o < 16; o <<= 1) {
                    vs += __shfl_xor(vs, o);
                    vd += __shfl_xor(vd, o);
                }
                if ((lane & 15) == 0) {
                    int m = row0 + wm * (BM / WM) + mf * 16 + ((lane >> 4) << 2) + r2;
                    atomicAdd(&sdot_s[m], vs);
                    atomicAdd(&sdot_d[m], vd);
                }
            }
        }
    }
}

// ---------------------------------------------------------------- layer-2 GEMM: 2 waves, wave tile 64x128
// LDS traffic/K-step 48 KB (A un-duplicated) vs 64 KB for the 2x2 layout ->
// MFMA:LDS ratio 3:1 -> 4:1. ld==K==ldC==1024 hardcoded. SDOT fused.
__global__ __launch_bounds__(128, 2)
void gemm2_mfma(const __hip_bfloat16* __restrict__ Ah,
                const __hip_bfloat16* __restrict__ Al,
                const __hip_bfloat16* __restrict__ Bh,
                const __hip_bfloat16* __restrict__ Bl,
                float* __restrict__ C, int M,
                const float* __restrict__ adot_s, const float* __restrict__ adot_d,
                float* __restrict__ sdot_s, float* __restrict__ sdot_d,
                int swzNB) {
    constexpr int TAB = 128 * 64;          // 8 KB per tensor tile
    __shared__ char lds[4 * TAB];          // 32 KB
    char* sAh = lds;
    char* sAl = lds + TAB;
    char* sBh = lds + 2 * TAB;
    char* sBl = lds + 3 * TAB;

    const int tid = threadIdx.x;
    const int lane = tid & 63;
    const int w = tid >> 6;                // 0..1

    int bx = blockIdx.x, by = blockIdx.y;
    {   // bijective chunked XCD swizzle (swzNB % 8 == 0)
        int gx = gridDim.x;
        int lin = by * gx + bx;
        int c = lin & 7, i = lin >> 3;
        int nl = c * (swzNB >> 3) + i;
        bx = nl % gx;
        by = nl / gx;
    }
    const int row0 = by * 128;
    const int col0 = bx * 128;

    const int Rl = lane >> 3;
    const int sl = lane & 7;
    const int rl = 2 * Rl + (sl >> 2);
    const int psrc = (sl & 3) ^ (Rl & 3);  // chunk-row*8 % 4 == 0 -> lc-independent

    // per-tensor staging bases: wave w stages chunks cl = w + 2j, j=0..3
    const __hip_bfloat16* pT0 = Ah + (size_t)(row0 + w * 16 + rl) * 1024 + psrc * 8;
    const __hip_bfloat16* pT1 = Al + (size_t)(row0 + w * 16 + rl) * 1024 + psrc * 8;
    const __hip_bfloat16* pT2 = Bh + (size_t)(col0 + w * 16 + rl) * 1024 + psrc * 8;
    const __hip_bfloat16* pT3 = Bl + (size_t)(col0 + w * 16 + rl) * 1024 + psrc * 8;
    char* l0 = sAh + w * 1024;
    char* l1 = sAl + w * 1024;
    char* l2 = sBh + w * 1024;
    char* l3 = sBl + w * 1024;

    f32x4 acc[4][8];
    #pragma unroll
    for (int i = 0; i < 4; ++i)
        #pragma unroll
        for (int j = 0; j < 8; ++j) acc[i][j] = (f32x4){0.f, 0.f, 0.f, 0.f};

    for (int k0 = 0; k0 < 1024; k0 += 32) {
        __syncthreads();
        #pragma unroll
        for (int j = 0; j < 4; ++j) {
            GLD16(pT0 + (size_t)j * 32768, l0 + j * 2048);
            GLD16(pT1 + (size_t)j * 32768, l1 + j * 2048);
            GLD16(pT2 + (size_t)j * 32768, l2 + j * 2048);
            GLD16(pT3 + (size_t)j * 32768, l3 + j * 2048);
        }
        pT0 += 32; pT1 += 32; pT2 += 32; pT3 += 32;
        __syncthreads();
        short8v ah[4], al[4];
        #pragma unroll
        for (int mf = 0; mf < 4; ++mf) {
            int r = w * 64 + mf * 16 + (lane & 15);
            int p = lane >> 4;
            int off = (r >> 1) * 128 + (r & 1) * 64 + ((p ^ ((r >> 1) & 3)) << 4);
            ah[mf] = *(const short8v*)(sAh + off);
            al[mf] = *(const short8v*)(sAl + off);
        }
        #pragma unroll
        for (int nf = 0; nf < 8; ++nf) {
            int r = nf * 16 + (lane & 15);
            int p = lane >> 4;
            int off = (r >> 1) * 128 + (r & 1) * 64 + ((p ^ ((r >> 1) & 3)) << 4);
            short8v bh = *(const short8v*)(sBh + off);
            short8v bl = *(const short8v*)(sBl + off);
            #pragma unroll
            for (int mf = 0; mf < 4; ++mf) {
                acc[mf][nf] = __builtin_amdgcn_mfma_f32_16x16x32_bf16(ah[mf], bh, acc[mf][nf], 0, 0, 0);
                acc[mf][nf] = __builtin_amdgcn_mfma_f32_16x16x32_bf16(ah[mf], bl, acc[mf][nf], 0, 0, 0);
                acc[mf][nf] = __builtin_amdgcn_mfma_f32_16x16x32_bf16(al[mf], bh, acc[mf][nf], 0, 0, 0);
            }
        }
    }

    float ps[4][4], pd[4][4];
    #pragma unroll
    for (int mf = 0; mf < 4; ++mf)
        #pragma unroll
        for (int r2 = 0; r2 < 4; ++r2) { ps[mf][r2] = 0.f; pd[mf][r2] = 0.f; }

    #pragma unroll
    for (int mf = 0; mf < 4; ++mf) {
        int m = row0 + w * 64 + mf * 16 + ((lane >> 4) << 2);
        #pragma unroll
        for (int nf = 0; nf < 8; ++nf) {
            int gcol = col0 + nf * 16 + (lane & 15);
            f32x4 v = acc[mf][nf];
            float as = adot_s[gcol], ad = adot_d[gcol];
            #pragma unroll
            for (int r2 = 0; r2 < 4; ++r2) {
                ps[mf][r2] += v[r2] * as;
                pd[mf][r2] += v[r2] * ad;
            }
            #pragma unroll
            for (int r2 = 0; r2 < 4; ++r2) {
                if (m + r2 < M) C[(size_t)(m + r2) * 1024 + gcol] = v[r2];
            }
        }
    }
    #pragma unroll
    for (int mf = 0; mf < 4; ++mf) {
        #pragma unroll
        for (int r2 = 0; r2 < 4; ++r2) {
            float vs = ps[mf][r2], vd = pd[mf][r2];
            #pragma unroll
            for (int o = 1; o < 16; o <<= 1) {
                vs += __shfl_xor(vs, o);
                vd += __shfl_xor(vd, o);
            }
            if ((lane & 15) == 0) {
                int m = row0 + w * 64 + mf * 16 + ((lane >> 4) << 2) + r2;
                atomicAdd(&sdot_s[m], vs);
                atomicAdd(&sdot_d[m], vd);
            }
        }
    }
}

// ---------------------------------------------------------------- s_src/s_dst (layer 3)
template <int C>
__global__ void sdot_kernel(const float* __restrict__ h, int ld,
                            const float* __restrict__ a_src,
                            const float* __restrict__ a_dst,
                            float* __restrict__ ssrc, float* __restrict__ sdst) {
    int n = blockIdx.x;
    int lane = threadIdx.x;        // 64
    const float* hp = h + (size_t)n * ld;
    float p1 = 0.f, p2 = 0.f;
    for (int c = lane; c < C; c += 64) {
        float v = hp[c];
        p1 += v * a_src[c];
        p2 += v * a_dst[c];
    }
    #pragma unroll
    for (int off = 32; off; off >>= 1) {
        p1 += __shfl_down(p1, off);
        p2 += __shfl_down(p2, off);
    }
    if (lane == 0) { ssrc[n] = p1; sdst[n] = p2; }
}

// ---------------------------------------------------------------- coef precompute (H=1) -> packed {src, coef}
__global__ void coef_kernel(const float* __restrict__ ssrc,
                            const float* __restrict__ sdst,
                            const int* __restrict__ row_ptr,
                            const int* __restrict__ esrc,
                            int2* __restrict__ ecp) {
    int n = blockIdx.x, lane = threadIdx.x;   // 64 threads
    int row = row_ptr[n], end = row_ptr[n + 1];
    float sd = sdst[n];
    float mymax = -1e30f;
    for (int e = row + lane; e < end; e += 64) {
        int s = esrc[e];
        float a = ssrc[s] + sd;
        a = (a >= 0.f) ? a : 0.2f * a;
        ecp[e].x = s;
        ecp[e].y = __float_as_int(a);
        mymax = fmaxf(mymax, a);
    }
    #pragma unroll
    for (int o = 32; o; o >>= 1) mymax = fmaxf(mymax, __shfl_xor(mymax, o));
    float mysum = 0.f;
    for (int e = row + lane; e < end; e += 64) {
        float ex = __expf(__int_as_float(ecp[e].y) - mymax);
        ecp[e].y = __float_as_int(ex);
        mysum += ex;
    }
    #pragma unroll
    for (int o = 32; o; o >>= 1) mysum += __shfl_xor(mysum, o);
    float inv = 1.f / mysum;
    for (int e = row + lane; e < end; e += 64)
        ecp[e].y = __float_as_int(__int_as_float(ecp[e].y) * inv);
}

// ---------------------------------------------------------------- sliced aggregation, layer 2
__global__ void sliceagg2_kernel(const float* __restrict__ h,
                                 const int2* __restrict__ ecp,
                                 const int* __restrict__ row_ptr,
                                 const float* __restrict__ bias,
                                 __hip_bfloat16* __restrict__ oh,
                                 __hip_bfloat16* __restrict__ ol,
                                 int ch0) {
    int bx = blockIdx.x;
    int slice = bx & 7, nb = bx >> 3;
    int tid = threadIdx.x;          // 256
    int n = nb * 16 + (tid >> 4);
    int j = tid & 15;
    int col = ch0 + slice * 64 + j * 4;
    int row = row_ptr[n], end = row_ptr[n + 1];
    float4 acc = {0.f, 0.f, 0.f, 0.f};
    int e = row;
    for (; e + 4 <= end; e += 4) {
        int2 p0 = ecp[e], p1 = ecp[e + 1], p2 = ecp[e + 2], p3 = ecp[e + 3];
        float c0 = __int_as_float(p0.y), c1 = __int_as_float(p1.y);
        float c2 = __int_as_float(p2.y), c3 = __int_as_float(p3.y);
        const float4 v0 = *reinterpret_cast<const float4*>(h + (size_t)p0.x * DBIG + col);
        const float4 v1 = *reinterpret_cast<const float4*>(h + (size_t)p1.x * DBIG + col);
        const float4 v2 = *reinterpret_cast<const float4*>(h + (size_t)p2.x * DBIG + col);
        const float4 v3 = *reinterpret_cast<const float4*>(h + (size_t)p3.x * DBIG + col);
        acc.x += c0 * v0.x + c1 * v1.x + c2 * v2.x + c3 * v3.x;
        acc.y += c0 * v0.y + c1 * v1.y + c2 * v2.y + c3 * v3.y;
        acc.z += c0 * v0.z + c1 * v1.z + c2 * v2.z + c3 * v3.z;
        acc.w += c0 * v0.w + c1 * v1.w + c2 * v2.w + c3 * v3.w;
    }
    for (; e < end; ++e) {
        int2 p0 = ecp[e];
        float c0 = __int_as_float(p0.y);
        const float4 v0 = *reinterpret_cast<const float4*>(h + (size_t)p0.x * DBIG + col);
        acc.x += c0 * v0.x; acc.y += c0 * v0.y;
        acc.z += c0 * v0.z; acc.w += c0 * v0.w;
    }
    const float4 bv = *reinterpret_cast<const float4*>(bias + col);
    float vals[4] = {acc.x + bv.x, acc.y + bv.y, acc.z + bv.z, acc.w + bv.w};
    unsigned short hs[4], ls[4];
    #pragma unroll
    for (int r = 0; r < 4; ++r) {
        float o = (vals[r] > 0.f) ? vals[r] : __expf(vals[r]) - 1.f;  // ELU
        __hip_bfloat16 hb = __float2bfloat16(o);
        hs[r] = __bfloat16_as_ushort(hb);
        ls[r] = __bfloat16_as_ushort(__float2bfloat16(o - __bfloat162float(hb)));
    }
    *(u16x4*)(oh + (size_t)n * DBIG + col) = (u16x4){hs[0], hs[1], hs[2], hs[3]};
    *(u16x4*)(ol + (size_t)n * DBIG + col) = (u16x4){ls[0], ls[1], ls[2], ls[3]};
}

// ---------------------------------------------------------------- sliced aggregation, layer 3
__global__ void sliceagg3_kernel(const float* __restrict__ h,
                                 const int2* __restrict__ ecp,
                                 const int* __restrict__ row_ptr,
                                 const float* __restrict__ bias,
                                 float* __restrict__ out) {
    int bx = blockIdx.x;
    int slice = bx & 1, nb = bx >> 1;
    int tid = threadIdx.x;          // 256
    int n = nb * 16 + (tid >> 4);
    int j = tid & 15;
    int col = slice * 64 + j * 4;
    int row = row_ptr[n], end = row_ptr[n + 1];
    float4 acc = {0.f, 0.f, 0.f, 0.f};
    int e = row;
    for (; e + 4 <= end; e += 4) {
        int2 p0 = ecp[e], p1 = ecp[e + 1], p2 = ecp[e + 2], p3 = ecp[e + 3];
        float c0 = __int_as_float(p0.y), c1 = __int_as_float(p1.y);
        float c2 = __int_as_float(p2.y), c3 = __int_as_float(p3.y);
        const float4 v0 = *reinterpret_cast<const float4*>(h + (size_t)p0.x * 128 + col);
        const float4 v1 = *reinterpret_cast<const float4*>(h + (size_t)p1.x * 128 + col);
        const float4 v2 = *reinterpret_cast<const float4*>(h + (size_t)p2.x * 128 + col);
        const float4 v3 = *reinterpret_cast<const float4*>(h + (size_t)p3.x * 128 + col);
        acc.x += c0 * v0.x + c1 * v1.x + c2 * v2.x + c3 * v3.x;
        acc.y += c0 * v0.y + c1 * v1.y + c2 * v2.y + c3 * v3.y;
        acc.z += c0 * v0.z + c1 * v1.z + c2 * v2.z + c3 * v3.z;
        acc.w += c0 * v0.w + c1 * v1.w + c2 * v2.w + c3 * v3.w;
    }
    for (; e < end; ++e) {
        int2 p0 = ecp[e];
        float c0 = __int_as_float(p0.y);
        const float4 v0 = *reinterpret_cast<const float4*>(h + (size_t)p0.x * 128 + col);
        acc.x += c0 * v0.x; acc.y += c0 * v0.y;
        acc.z += c0 * v0.z; acc.w += c0 * v0.w;
    }
    float vals[4] = {acc.x, acc.y, acc.z, acc.w};
    #pragma unroll
    for (int r = 0; r < 4; ++r) {
        int c = col + r;
        if (c < NCLS) out[(size_t)n * NCLS + c] = vals[r] + bias[c];
    }
}

// ---------------------------------------------------------------- launcher
extern "C" void kernel_launch(void* const* d_in, const int* in_sizes, int n_in,
                              void* d_out, int out_size, void* d_ws, size_t ws_size,
                              hipStream_t stream) {
    const float* x      = (const float*)d_in[0];
    const int*   ei     = (const int*)d_in[1];
    const float* W1     = (const float*)d_in[2];
    const float* a_src1 = (const float*)d_in[3];
    const float* a_dst1 = (const float*)d_in[4];
    const float* b1     = (const float*)d_in[5];
    const float* W2     = (const float*)d_in[6];
    const float* a_src2 = (const float*)d_in[7];
    const float* a_dst2 = (const float*)d_in[8];
    const float* b2     = (const float*)d_in[9];
    const float* W3     = (const float*)d_in[10];
    const float* a_src3 = (const float*)d_in[11];
    const float* a_dst3 = (const float*)d_in[12];
    const float* b3     = (const float*)d_in[13];
    float* out = (float*)d_out;

    const int N = NNODES, E = NEDGES, Etot = NEDGES + NNODES;

    // ---- workspace layout
    char* p = (char*)d_ws;
    float* H_buf = (float*)p;                 p += (size_t)N * DBIG * 4;       // 40.96 MB
    __hip_bfloat16* AH = (__hip_bfloat16*)p;  p += (size_t)MPAD * DBIG * 2;    // 20.7 MB
    __hip_bfloat16* AL = (__hip_bfloat16*)p;  p += (size_t)MPAD * DBIG * 2;
    __hip_bfloat16* BTH = (__hip_bfloat16*)p; p += (size_t)1024 * 1024 * 2;    // 2 MB
    __hip_bfloat16* BTL = (__hip_bfloat16*)p; p += (size_t)1024 * 1024 * 2;
    float* ssrc = (float*)p;                  p += (size_t)N * 8 * 4;
    float* sdst = (float*)p;                  p += (size_t)N * 8 * 4;
    float* wfold = (float*)p;                 p += 16 * 64 * 4;
    int* row_ptr = (int*)p;                   p += 40064;
    int* cursor = (int*)p;                    p += 2 * N * 4;                  // cursor + cursor2
    int* cursor2 = cursor + N;
    int* esrc = (int*)p;                      p += (size_t)Etot * 4;
    int2* ecp = (int2*)p;                     p += (size_t)Etot * 8;           // packed {src, coef}
    __hip_bfloat16* YH = (__hip_bfloat16*)H_buf;         // aliases H_buf
    __hip_bfloat16* YL = YH + (size_t)8 * MPAD * 64;
    float* H3 = (float*)H_buf;                            // [MPAD][128] f32, 5.2MB

    // ---- CSR by dst (single memset zeroes both cursors)
    hipMemsetAsync(cursor, 0, 2 * N * sizeof(int), stream);
    hist_kernel<<<(Etot + 255) / 256, 256, 0, stream>>>(ei, cursor, E, N);
    scan_kernel<<<1, 1024, 0, stream>>>(cursor, row_ptr, N);
    scatter_kernel<<<(Etot + 255) / 256, 256, 0, stream>>>(ei, row_ptr, cursor2, esrc, E, N);

    // ---- layer 1 (factored): s-dots from X, aggregate X, then 8 head-GEMMs
    fold_kernel<<<16, 64, 0, stream>>>(W1, a_src1, a_dst1, wfold);
    sdot1x_kernel<<<(N + 15) / 16, 256, 0, stream>>>(x, wfold, ssrc, sdst);
    agg1_kernel<<<MPAD, 64, 0, stream>>>(x, ssrc, sdst, row_ptr, esrc, YH, YL);
    {
        dim3 tg(1, 16);
        tsplit_kernel<<<tg, 256, 0, stream>>>(W1, F_IN, DBIG, 64, BTH, BTL);
        dim3 grid(1, MPAD / 128, 8);
        // prologue also zeroes ssrc+sdst (2*N*8 floats) for gemm2's SDOT atomics
        gemm_mfma<128, 128, 2, 2, true, true, false><<<grid, 256, 0, stream>>>(
            YH, YL, 64, (long)MPAD * 64, BTH, BTL, 64, (long)HIDDEN * 64,
            nullptr, DBIG, MPAD, HIDDEN, 64, HIDDEN, b1, AH, AL, 0,
            nullptr, nullptr, nullptr, nullptr, ssrc, 2 * N * 8);
    }
    // ---- layer 2: 1024 -> 1024 (2-wave GEMM, s-dots fused via atomics)
    {
        dim3 tg(16, 16);
        tsplit_kernel<<<tg, 256, 0, stream>>>(W2, DBIG, DBIG, DBIG, BTH, BTL);
        dim3 grid(DBIG / 128, MPAD / 128);      // 8 x 79 = 632 blocks
        gemm2_mfma<<<grid, 128, 0, stream>>>(
            AH, AL, BTH, BTL, H_buf, N, a_src2, a_dst2, ssrc, sdst, 632);
        coef_kernel<<<N, 64, 0, stream>>>(ssrc, sdst, row_ptr, esrc, ecp);
        // two sequential half-passes keep each XCD's working set at 2.56 MB
        sliceagg2_kernel<<<8 * (N / 16), 256, 0, stream>>>(
            H_buf, ecp, row_ptr, b2, AH, AL, 0);
        sliceagg2_kernel<<<8 * (N / 16), 256, 0, stream>>>(
            H_buf, ecp, row_ptr, b2, AH, AL, 512);
    }
    // ---- layer 3: 1024 -> 121 (C padded to ld=128), mean(=identity), no ELU
    {
        dim3 tg(16, 2);
        tsplit_kernel<<<tg, 256, 0, stream>>>(W3, DBIG, NCLS, DBIG, BTH, BTL);
        dim3 grid(4, MPAD / 64, 1);   // 4 x 158 = 632 blocks
        gemm_mfma<64, 32, 2, 2, false, false, false><<<grid, 256, 0, stream>>>(
            AH, AL, DBIG, 0, BTH, BTL, DBIG, 0,
            H3, 128, MPAD, 128, DBIG, 0, nullptr, nullptr, nullptr, 632,
            nullptr, nullptr, nullptr, nullptr, nullptr, 0);
        sdot_kernel<NCLS><<<N, 64, 0, stream>>>(H3, 128, a_src3, a_dst3, ssrc, sdst);
        coef_kernel<<<N, 64, 0, stream>>>(ssrc, sdst, row_ptr, esrc, ecp);
        sliceagg3_kernel<<<2 * (N / 16), 256, 0, stream>>>(
            H3, ecp, row_ptr, b3, out);
    }
}

// Round 12
// 287.527 us; speedup vs baseline: 1.0326x; 1.0326x over previous
//
#include <hip/hip_runtime.h>
#include <hip/hip_bf16.h>

#define NNODES 10000
#define NEDGES 160000
#define F_IN   50
#define HIDDEN 128
#define NCLS   121
#define DBIG   1024   // 8*128
#define MPAD   10112  // 79*128 = 158*64

typedef __attribute__((ext_vector_type(8))) short short8v;
typedef __attribute__((ext_vector_type(4))) float f32x4;
typedef __attribute__((ext_vector_type(4))) unsigned short u16x4;

#define GLD16(gsrc, ldst) \
  __builtin_amdgcn_global_load_lds((__attribute__((address_space(1))) const void*)(const void*)(gsrc), \
                                   (__attribute__((address_space(3))) void*)(void*)(ldst), 16, 0, 0)

// ---------------------------------------------------------------- CSR build
__global__ void hist_kernel(const int* __restrict__ ei, int* __restrict__ cnt,
                            int E_, int N_) {
    int e = blockIdx.x * blockDim.x + threadIdx.x;
    if (e >= E_ + N_) return;
    int dst = (e < E_) ? ei[E_ + e] : (e - E_);
    atomicAdd(&cnt[dst], 1);
}

// single-pass scan: 1024 threads x 10-elem local prefix + one shuffle round
__global__ void scan_kernel(const int* __restrict__ cnt, int* __restrict__ row_ptr,
                            int n) {
    constexpr int CHUNK = 10;      // 1024*10 = 10240 >= n+1
    __shared__ int sums[16];
    int tid = threadIdx.x, lane = tid & 63, wid = tid >> 6;
    int base = tid * CHUNK;
    int loc[CHUNK];
    int tot = 0;
    #pragma unroll
    for (int i = 0; i < CHUNK; ++i) {
        int idx = base + i;
        int v = (idx < n) ? cnt[idx] : 0;
        loc[i] = tot;              // exclusive local prefix
        tot += v;
    }
    int x = tot;
    #pragma unroll
    for (int o = 1; o < 64; o <<= 1) {
        int t = __shfl_up(x, o);
        if (lane >= o) x += t;
    }
    if (lane == 63) sums[wid] = x;
    __syncthreads();
    if (tid == 0) {
        int acc = 0;
        #pragma unroll
        for (int k = 0; k < 16; ++k) { int t = sums[k]; sums[k] = acc; acc += t; }
    }
    __syncthreads();
    int offset = sums[wid] + x - tot;   // exclusive prefix at base
    #pragma unroll
    for (int i = 0; i < CHUNK; ++i) {
        int idx = base + i;
        if (idx <= n) row_ptr[idx] = offset + loc[i];  // idx==n -> total
    }
}

__global__ void scatter_kernel(const int* __restrict__ ei,
                               const int* __restrict__ row_ptr,
                               int* __restrict__ cursor, int* __restrict__ esrc,
                               int E_, int N_) {
    int e = blockIdx.x * blockDim.x + threadIdx.x;
    if (e >= E_ + N_) return;
    int s, d;
    if (e < E_) { s = ei[e]; d = ei[E_ + e]; } else { s = d = e - E_; }
    int pos = row_ptr[d] + atomicAdd(&cursor[d], 1);
    esrc[pos] = s;
}

// ---------------------------------------------------------------- layer-1 folds
__global__ void fold_kernel(const float* __restrict__ W1,
                            const float* __restrict__ a_src,
                            const float* __restrict__ a_dst,
                            float* __restrict__ wfold) {
    int b = blockIdx.x;           // 16 blocks
    int h = b & 7, which = b >> 3;
    int k = threadIdx.x;          // 64
    const float* a = which ? a_dst : a_src;
    float dot = 0.f;
    if (k < F_IN) {
        for (int c = 0; c < HIDDEN; ++c)
            dot += W1[(size_t)k * DBIG + h * HIDDEN + c] * a[h * HIDDEN + c];
    }
    wfold[(which * 8 + h) * 64 + k] = dot;
}

__global__ void sdot1x_kernel(const float* __restrict__ x,
                              const float* __restrict__ wfold,
                              float* __restrict__ ssrc, float* __restrict__ sdst) {
    __shared__ float sh_x[16][52];
    __shared__ float sh_w[16][64];
    int tid = threadIdx.x;        // 256
    int n0 = blockIdx.x * 16;
    for (int i = tid; i < 16 * 64; i += 256) sh_w[i >> 6][i & 63] = wfold[i];
    for (int i = tid; i < 16 * F_IN; i += 256) {
        int nl = i / F_IN, k = i % F_IN;
        int n = n0 + nl;
        sh_x[nl][k] = (n < NNODES) ? x[(size_t)n * F_IN + k] : 0.f;
    }
    __syncthreads();
    int nl = tid >> 4, o = tid & 15;
    int n = n0 + nl;
    if (n >= NNODES) return;
    float s = 0.f;
    #pragma unroll
    for (int k = 0; k < F_IN; ++k) s += sh_x[nl][k] * sh_w[o][k];
    if (o < 8) ssrc[n * 8 + o] = s;
    else       sdst[n * 8 + (o - 8)] = s;
}

// layer-1 aggregation over X (50-wide). grid = MPAD (pad blocks write zeros).
__global__ void agg1_kernel(const float* __restrict__ x,
                            const float* __restrict__ ssrc,
                            const float* __restrict__ sdst,
                            const int* __restrict__ row_ptr,
                            const int* __restrict__ esrc,
                            __hip_bfloat16* __restrict__ YH,
                            __hip_bfloat16* __restrict__ YL) {
    int n = blockIdx.x;
    int tid = threadIdx.x;        // 64
    if (n >= NNODES) {            // pad rows -> zeros
        #pragma unroll
        for (int h = 0; h < 8; ++h) {
            size_t o = ((size_t)h * MPAD + n) * 64 + tid;
            YH[o] = __float2bfloat16(0.f);
            YL[o] = __float2bfloat16(0.f);
        }
        return;
    }
    __shared__ float m_s[8], inv_s[8], sd_s[8];
    __shared__ int sidx[64];
    __shared__ float coef[64][9];
    int row = row_ptr[n], end = row_ptr[n + 1];
    {
        int el = tid >> 3, hh = tid & 7;
        float sd = sdst[n * 8 + hh];
        float mymax = -1e30f;
        for (int e = row + el; e < end; e += 8) {
            float a = ssrc[esrc[e] * 8 + hh] + sd;
            a = (a >= 0.f) ? a : 0.2f * a;
            mymax = fmaxf(mymax, a);
        }
        #pragma unroll
        for (int o = 8; o < 64; o <<= 1) mymax = fmaxf(mymax, __shfl_xor(mymax, o));
        float mysum = 0.f;
        for (int e = row + el; e < end; e += 8) {
            float a = ssrc[esrc[e] * 8 + hh] + sd;
            a = (a >= 0.f) ? a : 0.2f * a;
            mysum += __expf(a - mymax);
        }
        #pragma unroll
        for (int o = 8; o < 64; o <<= 1) mysum += __shfl_xor(mysum, o);
        if (el == 0) { m_s[hh] = mymax; inv_s[hh] = 1.f / mysum; sd_s[hh] = sd; }
    }
    __syncthreads();
    float acc[8] = {};
    for (int cs = row; cs < end; cs += 64) {
        int nE = min(64, end - cs);
        if (tid < nE) {
            int s = esrc[cs + tid];
            sidx[tid] = s;
            #pragma unroll
            for (int h = 0; h < 8; ++h) {
                float a = ssrc[s * 8 + h] + sd_s[h];
                a = (a >= 0.f) ? a : 0.2f * a;
                coef[tid][h] = __expf(a - m_s[h]) * inv_s[h];
            }
        }
        __syncthreads();
        if (tid < F_IN) {
            for (int i = 0; i < nE; ++i) {
                float xv = x[(size_t)sidx[i] * F_IN + tid];
                #pragma unroll
                for (int h = 0; h < 8; ++h) acc[h] += coef[i][h] * xv;
            }
        }
        __syncthreads();
    }
    #pragma unroll
    for (int h = 0; h < 8; ++h) {
        float v = acc[h];
        __hip_bfloat16 hb = __float2bfloat16(v);
        size_t o = ((size_t)h * MPAD + n) * 64 + tid;
        YH[o] = hb;
        YL[o] = __float2bfloat16(v - __bfloat162float(hb));
    }
}

// ---------------------------------------------------------------- weight prep
__global__ void tsplit_kernel(const float* __restrict__ W, int K, int Nn, int Kpad,
                              __hip_bfloat16* __restrict__ bh,
                              __hip_bfloat16* __restrict__ bl) {
    __shared__ float sh[64][65];
    int k0 = blockIdx.x * 64, n0 = blockIdx.y * 64;
    int tid = threadIdx.x;
    int cc = tid & 63, rr = tid >> 6;
    #pragma unroll
    for (int i = 0; i < 16; ++i) {
        int r = rr + i * 4;
        int k = k0 + r, n = n0 + cc;
        sh[r][cc] = (k < K && n < Nn) ? W[(size_t)k * Nn + n] : 0.f;
    }
    __syncthreads();
    #pragma unroll
    for (int i = 0; i < 16; ++i) {
        int r = rr + i * 4;
        float v = sh[cc][r];
        __hip_bfloat16 h = __float2bfloat16(v);
        size_t o = (size_t)(n0 + r) * Kpad + k0 + cc;
        bh[o] = h;
        bl[o] = __float2bfloat16(v - __bfloat162float(h));
    }
}

// ---------------------------------------------------------------- MFMA GEMM (generic, all layers)
// BK=32 (64B rows), WM x WN wave grid (WM*WN==4, 256 thr).
// LDS paired super-rows: phys(r,p)=(r>>1)*128+(r&1)*64+((p^((r>>1)&3))<<4)
// Inverse swizzle on the GLOBAL source of global_load_lds (rule 21).
// swzNB>0: bijective chunked XCD swizzle (T1) - requires swzNB%8==0.
// SDOT: fuse s_src/s_dst row dots into the epilogue via 16-lane reduce+atomicAdd.
// zeroPtr/zeroCnt: prologue zero-fill of a downstream accumulator buffer.
template <int BM, int BN, int WM, int WN, bool EPI, bool MASKC, bool SDOT>
__global__ __launch_bounds__(256, 4)
void gemm_mfma(const __hip_bfloat16* __restrict__ Ah,
               const __hip_bfloat16* __restrict__ Al, int ldA, long sAz,
               const __hip_bfloat16* __restrict__ Bh,
               const __hip_bfloat16* __restrict__ Bl, int ldB, long sBz,
               float* __restrict__ C, int ldC, int M, int Nn, int K, int colPerZ,
               const float* __restrict__ bias,
               __hip_bfloat16* __restrict__ OH, __hip_bfloat16* __restrict__ OL,
               int swzNB,
               const float* __restrict__ adot_s, const float* __restrict__ adot_d,
               float* __restrict__ sdot_s, float* __restrict__ sdot_d,
               float* __restrict__ zeroPtr, int zeroCnt) {
    constexpr int MF = BM / (WM * 16);
    constexpr int NF = BN / (WN * 16);
    constexpr int TAB = BM * 64;   // bytes per tile (BM rows x 64B)
    constexpr int TBB = BN * 64;
    __shared__ char lds[2 * TAB + 2 * TBB];
    char* sAh = lds;
    char* sAl = lds + TAB;
    char* sBh = lds + 2 * TAB;
    char* sBl = lds + 2 * TAB + TBB;

    const int tid = threadIdx.x;
    if (zeroPtr) {
        int lb = ((blockIdx.z * gridDim.y + blockIdx.y) * gridDim.x + blockIdx.x)
                     * (int)blockDim.x + tid;
        if (lb < zeroCnt) zeroPtr[lb] = 0.f;
    }

    const int z = blockIdx.z;
    Ah += (size_t)z * sAz; Al += (size_t)z * sAz;
    Bh += (size_t)z * sBz; Bl += (size_t)z * sBz;

    int bx = blockIdx.x, by = blockIdx.y;
    if (swzNB) {
        int gx = gridDim.x;
        int lin = by * gx + bx;
        int c = lin & 7, i = lin >> 3;
        int nl = c * (swzNB >> 3) + i;
        bx = nl % gx;
        by = nl / gx;
    }

    const int lane = tid & 63;
    const int w = tid >> 6;
    const int wm = w / WN, wn = w % WN;
    const int row0 = by * BM;
    const int col0 = bx * BN;

    constexpr int nchA = BM / 16, nchB = BN / 16;
    constexpr int NCH = 2 * nchA + 2 * nchB;
    constexpr int NIT = NCH / 4;

    const int Rl = lane >> 3;
    const int sl = lane & 7;
    const int rl = 2 * Rl + (sl >> 2);

    const __hip_bfloat16* gsrc[NIT];
    char* ldsp[NIT];
    #pragma unroll
    for (int it = 0; it < NIT; ++it) {
        int lc = w + it * 4;
        const __hip_bfloat16* g; char* base; int ld; int r0;
        if (lc < nchA)              { g = Ah; base = sAh; ld = ldA; r0 = row0; }
        else if ((lc -= nchA) < nchA){ g = Al; base = sAl; ld = ldA; r0 = row0; }
        else if ((lc -= nchA) < nchB){ g = Bh; base = sBh; ld = ldB; r0 = col0; }
        else { lc -= nchB;            g = Bl; base = sBl; ld = ldB; r0 = col0; }
        int R = lc * 8 + Rl;
        int rowt = lc * 16 + rl;
        int psrc = (sl & 3) ^ (R & 3);
        gsrc[it] = g + (size_t)(r0 + rowt) * ld + psrc * 8;
        ldsp[it] = base + lc * 1024;
    }

    f32x4 acc[MF][NF];
    #pragma unroll
    for (int i = 0; i < MF; ++i)
        #pragma unroll
        for (int j = 0; j < NF; ++j) acc[i][j] = (f32x4){0.f, 0.f, 0.f, 0.f};

    for (int k0 = 0; k0 < K; k0 += 32) {
        __syncthreads();
        #pragma unroll
        for (int it = 0; it < NIT; ++it) {
            GLD16(gsrc[it], ldsp[it]);
            gsrc[it] += 32;
        }
        __syncthreads();
        short8v ah[MF], al[MF];
        #pragma unroll
        for (int mf = 0; mf < MF; ++mf) {
            int r = wm * (BM / WM) + mf * 16 + (lane & 15);
            int p = lane >> 4;
            int off = (r >> 1) * 128 + (r & 1) * 64 + ((p ^ ((r >> 1) & 3)) << 4);
            ah[mf] = *(const short8v*)(sAh + off);
            al[mf] = *(const short8v*)(sAl + off);
        }
        #pragma unroll
        for (int nf = 0; nf < NF; ++nf) {
            int r = wn * (BN / WN) + nf * 16 + (lane & 15);
            int p = lane >> 4;
            int off = (r >> 1) * 128 + (r & 1) * 64 + ((p ^ ((r >> 1) & 3)) << 4);
            short8v bh = *(const short8v*)(sBh + off);
            short8v bl = *(const short8v*)(sBl + off);
            #pragma unroll
            for (int mf = 0; mf < MF; ++mf) {
                acc[mf][nf] = __builtin_amdgcn_mfma_f32_16x16x32_bf16(ah[mf], bh, acc[mf][nf], 0, 0, 0);
                acc[mf][nf] = __builtin_amdgcn_mfma_f32_16x16x32_bf16(ah[mf], bl, acc[mf][nf], 0, 0, 0);
                acc[mf][nf] = __builtin_amdgcn_mfma_f32_16x16x32_bf16(al[mf], bh, acc[mf][nf], 0, 0, 0);
            }
        }
    }

    float ps[MF][4], pd[MF][4];
    if (SDOT) {
        #pragma unroll
        for (int mf = 0; mf < MF; ++mf)
            #pragma unroll
            for (int r2 = 0; r2 < 4; ++r2) { ps[mf][r2] = 0.f; pd[mf][r2] = 0.f; }
    }

    #pragma unroll
    for (int mf = 0; mf < MF; ++mf) {
        int m = row0 + wm * (BM / WM) + mf * 16 + ((lane >> 4) << 2);
        #pragma unroll
        for (int nf = 0; nf < NF; ++nf) {
            int ln = col0 + wn * (BN / WN) + nf * 16 + (lane & 15);
            if (MASKC && ln >= Nn) continue;
            int gcol = z * colPerZ + ln;
            f32x4 v = acc[mf][nf];
            if (SDOT) {
                float as = adot_s[gcol], ad = adot_d[gcol];
                #pragma unroll
                for (int r2 = 0; r2 < 4; ++r2) {
                    ps[mf][r2] += v[r2] * as;
                    pd[mf][r2] += v[r2] * ad;
                }
            }
            if (EPI) {
                float bv = bias[gcol];
                #pragma unroll
                for (int r2 = 0; r2 < 4; ++r2) {
                    if (MASKC && m + r2 >= M) continue;
                    float o = v[r2] + bv;
                    o = (o > 0.f) ? o : __expf(o) - 1.f;
                    __hip_bfloat16 hb = __float2bfloat16(o);
                    size_t idx = (size_t)(m + r2) * ldC + gcol;
                    OH[idx] = hb;
                    OL[idx] = __float2bfloat16(o - __bfloat162float(hb));
                }
            } else {
                #pragma unroll
                for (int r2 = 0; r2 < 4; ++r2) {
                    if (MASKC && m + r2 >= M) continue;
                    C[(size_t)(m + r2) * ldC + gcol] = v[r2];
                }
            }
        }
    }

    if (SDOT) {
        #pragma unroll
        for (int mf = 0; mf < MF; ++mf) {
            #pragma unroll
            for (int r2 = 0; r2 < 4; ++r2) {
                float vs = ps[mf][r2], vd = pd[mf][r2];
                #pragma unroll
                for (int o = 1; o < 16; o <<= 1) {
                    vs += __shfl_xor(vs, o);
                    vd += __shfl_xor(vd, o);
                }
                if ((lane & 15) == 0) {
                    int m = row0 + wm * (BM / WM) + mf * 16 + ((lane >> 4) << 2) + r2;
                    atomicAdd(&sdot_s[m], vs);
                    atomicAdd(&sdot_d[m], vd);
                }
            }
        }
    }
}

// ---------------------------------------------------------------- s_src/s_dst (layer 3)
template <int C>
__global__ void sdot_kernel(const float* __restrict__ h, int ld,
                            const float* __restrict__ a_src,
                            const float* __restrict__ a_dst,
                            float* __restrict__ ssrc, float* __restrict__ sdst) {
    int n = blockIdx.x;
    int lane = threadIdx.x;        // 64
    const float* hp = h + (size_t)n * ld;
    float p1 = 0.f, p2 = 0.f;
    for (int c = lane; c < C; c += 64) {
        float v = hp[c];
        p1 += v * a_src[c];
        p2 += v * a_dst[c];
    }
    #pragma unroll
    for (int off = 32; off; off >>= 1) {
        p1 += __shfl_down(p1, off);
        p2 += __shfl_down(p2, off);
    }
    if (lane == 0) { ssrc[n] = p1; sdst[n] = p2; }
}

// ---------------------------------------------------------------- coef precompute (H=1) -> packed {src, coef}
__global__ void coef_kernel(const float* __restrict__ ssrc,
                            const float* __restrict__ sdst,
                            const int* __restrict__ row_ptr,
                            const int* __restrict__ esrc,
                            int2* __restrict__ ecp) {
    int n = blockIdx.x, lane = threadIdx.x;   // 64 threads
    int row = row_ptr[n], end = row_ptr[n + 1];
    float sd = sdst[n];
    float mymax = -1e30f;
    for (int e = row + lane; e < end; e += 64) {
        int s = esrc[e];
        float a = ssrc[s] + sd;
        a = (a >= 0.f) ? a : 0.2f * a;
        ecp[e].x = s;
        ecp[e].y = __float_as_int(a);
        mymax = fmaxf(mymax, a);
    }
    #pragma unroll
    for (int o = 32; o; o >>= 1) mymax = fmaxf(mymax, __shfl_xor(mymax, o));
    float mysum = 0.f;
    for (int e = row + lane; e < end; e += 64) {
        float ex = __expf(__int_as_float(ecp[e].y) - mymax);
        ecp[e].y = __float_as_int(ex);
        mysum += ex;
    }
    #pragma unroll
    for (int o = 32; o; o >>= 1) mysum += __shfl_xor(mysum, o);
    float inv = 1.f / mysum;
    for (int e = row + lane; e < end; e += 64)
        ecp[e].y = __float_as_int(__int_as_float(ecp[e].y) * inv);
}

// ---------------------------------------------------------------- sliced aggregation, layer 2
// 64-ch slices; slice = blockIdx.x & 7 pins each slice set to one XCD
// (round-robin dispatch) so the per-XCD L2 working set is 2.56 MB < 4 MB.
// 4-deep edge unroll + packed {src,coef} 8B loads.
__global__ void sliceagg2_kernel(const float* __restrict__ h,
                                 const int2* __restrict__ ecp,
                                 const int* __restrict__ row_ptr,
                                 const float* __restrict__ bias,
                                 __hip_bfloat16* __restrict__ oh,
                                 __hip_bfloat16* __restrict__ ol,
                                 int ch0) {
    int bx = blockIdx.x;
    int slice = bx & 7, nb = bx >> 3;
    int tid = threadIdx.x;          // 256
    int n = nb * 16 + (tid >> 4);
    int j = tid & 15;
    int col = ch0 + slice * 64 + j * 4;
    int row = row_ptr[n], end = row_ptr[n + 1];
    float4 acc = {0.f, 0.f, 0.f, 0.f};
    int e = row;
    for (; e + 4 <= end; e += 4) {
        int2 p0 = ecp[e], p1 = ecp[e + 1], p2 = ecp[e + 2], p3 = ecp[e + 3];
        float c0 = __int_as_float(p0.y), c1 = __int_as_float(p1.y);
        float c2 = __int_as_float(p2.y), c3 = __int_as_float(p3.y);
        const float4 v0 = *reinterpret_cast<const float4*>(h + (size_t)p0.x * DBIG + col);
        const float4 v1 = *reinterpret_cast<const float4*>(h + (size_t)p1.x * DBIG + col);
        const float4 v2 = *reinterpret_cast<const float4*>(h + (size_t)p2.x * DBIG + col);
        const float4 v3 = *reinterpret_cast<const float4*>(h + (size_t)p3.x * DBIG + col);
        acc.x += c0 * v0.x + c1 * v1.x + c2 * v2.x + c3 * v3.x;
        acc.y += c0 * v0.y + c1 * v1.y + c2 * v2.y + c3 * v3.y;
        acc.z += c0 * v0.z + c1 * v1.z + c2 * v2.z + c3 * v3.z;
        acc.w += c0 * v0.w + c1 * v1.w + c2 * v2.w + c3 * v3.w;
    }
    for (; e < end; ++e) {
        int2 p0 = ecp[e];
        float c0 = __int_as_float(p0.y);
        const float4 v0 = *reinterpret_cast<const float4*>(h + (size_t)p0.x * DBIG + col);
        acc.x += c0 * v0.x; acc.y += c0 * v0.y;
        acc.z += c0 * v0.z; acc.w += c0 * v0.w;
    }
    const float4 bv = *reinterpret_cast<const float4*>(bias + col);
    float vals[4] = {acc.x + bv.x, acc.y + bv.y, acc.z + bv.z, acc.w + bv.w};
    unsigned short hs[4], ls[4];
    #pragma unroll
    for (int r = 0; r < 4; ++r) {
        float o = (vals[r] > 0.f) ? vals[r] : __expf(vals[r]) - 1.f;  // ELU
        __hip_bfloat16 hb = __float2bfloat16(o);
        hs[r] = __bfloat16_as_ushort(hb);
        ls[r] = __bfloat16_as_ushort(__float2bfloat16(o - __bfloat162float(hb)));
    }
    *(u16x4*)(oh + (size_t)n * DBIG + col) = (u16x4){hs[0], hs[1], hs[2], hs[3]};
    *(u16x4*)(ol + (size_t)n * DBIG + col) = (u16x4){ls[0], ls[1], ls[2], ls[3]};
}

// ---------------------------------------------------------------- sliced aggregation, layer 3
__global__ void sliceagg3_kernel(const float* __restrict__ h,
                                 const int2* __restrict__ ecp,
                                 const int* __restrict__ row_ptr,
                                 const float* __restrict__ bias,
                                 float* __restrict__ out) {
    int bx = blockIdx.x;
    int slice = bx & 1, nb = bx >> 1;
    int tid = threadIdx.x;          // 256
    int n = nb * 16 + (tid >> 4);
    int j = tid & 15;
    int col = slice * 64 + j * 4;
    int row = row_ptr[n], end = row_ptr[n + 1];
    float4 acc = {0.f, 0.f, 0.f, 0.f};
    int e = row;
    for (; e + 4 <= end; e += 4) {
        int2 p0 = ecp[e], p1 = ecp[e + 1], p2 = ecp[e + 2], p3 = ecp[e + 3];
        float c0 = __int_as_float(p0.y), c1 = __int_as_float(p1.y);
        float c2 = __int_as_float(p2.y), c3 = __int_as_float(p3.y);
        const float4 v0 = *reinterpret_cast<const float4*>(h + (size_t)p0.x * 128 + col);
        const float4 v1 = *reinterpret_cast<const float4*>(h + (size_t)p1.x * 128 + col);
        const float4 v2 = *reinterpret_cast<const float4*>(h + (size_t)p2.x * 128 + col);
        const float4 v3 = *reinterpret_cast<const float4*>(h + (size_t)p3.x * 128 + col);
        acc.x += c0 * v0.x + c1 * v1.x + c2 * v2.x + c3 * v3.x;
        acc.y += c0 * v0.y + c1 * v1.y + c2 * v2.y + c3 * v3.y;
        acc.z += c0 * v0.z + c1 * v1.z + c2 * v2.z + c3 * v3.z;
        acc.w += c0 * v0.w + c1 * v1.w + c2 * v2.w + c3 * v3.w;
    }
    for (; e < end; ++e) {
        int2 p0 = ecp[e];
        float c0 = __int_as_float(p0.y);
        const float4 v0 = *reinterpret_cast<const float4*>(h + (size_t)p0.x * 128 + col);
        acc.x += c0 * v0.x; acc.y += c0 * v0.y;
        acc.z += c0 * v0.z; acc.w += c0 * v0.w;
    }
    float vals[4] = {acc.x, acc.y, acc.z, acc.w};
    #pragma unroll
    for (int r = 0; r < 4; ++r) {
        int c = col + r;
        if (c < NCLS) out[(size_t)n * NCLS + c] = vals[r] + bias[c];
    }
}

// ---------------------------------------------------------------- launcher
extern "C" void kernel_launch(void* const* d_in, const int* in_sizes, int n_in,
                              void* d_out, int out_size, void* d_ws, size_t ws_size,
                              hipStream_t stream) {
    const float* x      = (const float*)d_in[0];
    const int*   ei     = (const int*)d_in[1];
    const float* W1     = (const float*)d_in[2];
    const float* a_src1 = (const float*)d_in[3];
    const float* a_dst1 = (const float*)d_in[4];
    const float* b1     = (const float*)d_in[5];
    const float* W2     = (const float*)d_in[6];
    const float* a_src2 = (const float*)d_in[7];
    const float* a_dst2 = (const float*)d_in[8];
    const float* b2     = (const float*)d_in[9];
    const float* W3     = (const float*)d_in[10];
    const float* a_src3 = (const float*)d_in[11];
    const float* a_dst3 = (const float*)d_in[12];
    const float* b3     = (const float*)d_in[13];
    float* out = (float*)d_out;

    const int N = NNODES, E = NEDGES, Etot = NEDGES + NNODES;

    // ---- workspace layout
    char* p = (char*)d_ws;
    float* H_buf = (float*)p;                 p += (size_t)N * DBIG * 4;       // 40.96 MB
    __hip_bfloat16* AH = (__hip_bfloat16*)p;  p += (size_t)MPAD * DBIG * 2;    // 20.7 MB
    __hip_bfloat16* AL = (__hip_bfloat16*)p;  p += (size_t)MPAD * DBIG * 2;
    __hip_bfloat16* BTH = (__hip_bfloat16*)p; p += (size_t)1024 * 1024 * 2;    // 2 MB
    __hip_bfloat16* BTL = (__hip_bfloat16*)p; p += (size_t)1024 * 1024 * 2;
    float* ssrc = (float*)p;                  p += (size_t)N * 8 * 4;
    float* sdst = (float*)p;                  p += (size_t)N * 8 * 4;
    float* wfold = (float*)p;                 p += 16 * 64 * 4;
    int* row_ptr = (int*)p;                   p += 40064;
    int* cursor = (int*)p;                    p += 2 * N * 4;                  // cursor + cursor2
    int* cursor2 = cursor + N;
    int* esrc = (int*)p;                      p += (size_t)Etot * 4;
    int2* ecp = (int2*)p;                     p += (size_t)Etot * 8;           // packed {src, coef}
    __hip_bfloat16* YH = (__hip_bfloat16*)H_buf;         // aliases H_buf
    __hip_bfloat16* YL = YH + (size_t)8 * MPAD * 64;
    float* H3 = (float*)H_buf;                            // [MPAD][128] f32, 5.2MB

    // ---- CSR by dst (single memset zeroes both cursors)
    hipMemsetAsync(cursor, 0, 2 * N * sizeof(int), stream);
    hist_kernel<<<(Etot + 255) / 256, 256, 0, stream>>>(ei, cursor, E, N);
    scan_kernel<<<1, 1024, 0, stream>>>(cursor, row_ptr, N);
    scatter_kernel<<<(Etot + 255) / 256, 256, 0, stream>>>(ei, row_ptr, cursor2, esrc, E, N);

    // ---- layer 1 (factored): s-dots from X, aggregate X, then 8 head-GEMMs
    fold_kernel<<<16, 64, 0, stream>>>(W1, a_src1, a_dst1, wfold);
    sdot1x_kernel<<<(N + 15) / 16, 256, 0, stream>>>(x, wfold, ssrc, sdst);
    agg1_kernel<<<MPAD, 64, 0, stream>>>(x, ssrc, sdst, row_ptr, esrc, YH, YL);
    {
        dim3 tg(1, 16);
        tsplit_kernel<<<tg, 256, 0, stream>>>(W1, F_IN, DBIG, 64, BTH, BTL);
        dim3 grid(1, MPAD / 128, 8);
        // prologue also zeroes ssrc+sdst (2*N*8 floats) for gemm2's SDOT atomics
        gemm_mfma<128, 128, 2, 2, true, true, false><<<grid, 256, 0, stream>>>(
            YH, YL, 64, (long)MPAD * 64, BTH, BTL, 64, (long)HIDDEN * 64,
            nullptr, DBIG, MPAD, HIDDEN, 64, HIDDEN, b1, AH, AL, 0,
            nullptr, nullptr, nullptr, nullptr, ssrc, 2 * N * 8);
    }
    // ---- layer 2: 1024 -> 1024 (4-wave GEMM, s-dots fused via atomics)
    {
        dim3 tg(16, 16);
        tsplit_kernel<<<tg, 256, 0, stream>>>(W2, DBIG, DBIG, DBIG, BTH, BTL);
        dim3 grid(DBIG / 128, MPAD / 128, 1);   // 8 x 79 = 632 blocks
        gemm_mfma<128, 128, 2, 2, false, true, true><<<grid, 256, 0, stream>>>(
            AH, AL, DBIG, 0, BTH, BTL, DBIG, 0,
            H_buf, DBIG, N, DBIG, DBIG, 0, nullptr, nullptr, nullptr, 632,
            a_src2, a_dst2, ssrc, sdst, nullptr, 0);
        coef_kernel<<<N, 64, 0, stream>>>(ssrc, sdst, row_ptr, esrc, ecp);
        // two sequential half-passes keep each XCD's working set at 2.56 MB
        sliceagg2_kernel<<<8 * (N / 16), 256, 0, stream>>>(
            H_buf, ecp, row_ptr, b2, AH, AL, 0);
        sliceagg2_kernel<<<8 * (N / 16), 256, 0, stream>>>(
            H_buf, ecp, row_ptr, b2, AH, AL, 512);
    }
    // ---- layer 3: 1024 -> 121 (C padded to ld=128), mean(=identity), no ELU
    {
        dim3 tg(16, 2);
        tsplit_kernel<<<tg, 256, 0, stream>>>(W3, DBIG, NCLS, DBIG, BTH, BTL);
        dim3 grid(4, MPAD / 64, 1);   // 4 x 158 = 632 blocks
        gemm_mfma<64, 32, 2, 2, false, false, false><<<grid, 256, 0, stream>>>(
            AH, AL, DBIG, 0, BTH, BTL, DBIG, 0,
            H3, 128, MPAD, 128, DBIG, 0, nullptr, nullptr, nullptr, 632,
            nullptr, nullptr, nullptr, nullptr, nullptr, 0);
        sdot_kernel<NCLS><<<N, 64, 0, stream>>>(H3, 128, a_src3, a_dst3, ssrc, sdst);
        coef_kernel<<<N, 64, 0, stream>>>(ssrc, sdst, row_ptr, esrc, ecp);
        sliceagg3_kernel<<<2 * (N / 16), 256, 0, stream>>>(
            H3, ecp, row_ptr, b3, out);
    }
}